// Round 1
// baseline (154.847 us; speedup 1.0000x reference)
//
#include <hip/hip_runtime.h>
#include <math.h>

#define NUM_CLASSES 80
#define B_SZ 16
#define T_SZ 32

// ---- math helpers (match jax.nn.log_sigmoid / sigmoid in f32) ----
__device__ __forceinline__ float softplusf_(float x) {
    // log(1+exp(x)), stable
    return x > 0.f ? x + log1pf(expf(-x)) : log1pf(expf(x));
}
__device__ __forceinline__ float sigmoidf_(float x) {
    return 1.f / (1.f + expf(-x));
}
// focal_bce(x, t=0) = softplus(x) * sigmoid(x)^2
__device__ __forceinline__ float focal0(float x) {
    float s = sigmoidf_(x);
    return softplusf_(x) * s * s;
}
// focal_bce(x, t=1) = softplus(-x) * sigmoid(-x)^2
__device__ __forceinline__ float focal1(float x) {
    float s = sigmoidf_(-x);
    return softplusf_(-x) * s * s;
}

// Accumulator layout in ws (floats): per scale s, base = s*8:
// [0]=acc_xy [1]=acc_wh [2]=acc_cls [3]=acc_pos [4]=acc_neg [5]=n_obj

// ---- Kernel A: per-target assignment + object-cell losses ----
// 3 blocks (one per scale) x 512 threads (one per (b,t) target).
__global__ void obj_kernel(const float* __restrict__ p0,
                           const float* __restrict__ p1,
                           const float* __restrict__ p2,
                           const float* __restrict__ tgt,
                           float* __restrict__ acc) {
    const int s = blockIdx.x;
    const float* P = (s == 0) ? p0 : (s == 1 ? p1 : p2);
    const int H = (s == 0) ? 80 : (s == 1 ? 40 : 20);
    const int W = H;
    const int HW = H * W;

    // ANCHORS / 640 (f32, correctly rounded — matches numpy f32 division)
    const float AWC[3][3] = {{10.f/640.f, 16.f/640.f, 33.f/640.f},
                             {30.f/640.f, 62.f/640.f, 59.f/640.f},
                             {116.f/640.f,156.f/640.f,373.f/640.f}};
    const float AHC[3][3] = {{13.f/640.f, 30.f/640.f, 23.f/640.f},
                             {61.f/640.f, 45.f/640.f, 119.f/640.f},
                             {90.f/640.f, 198.f/640.f, 326.f/640.f}};

    __shared__ int   s_cell[B_SZ * T_SZ];
    __shared__ int   s_cls [B_SZ * T_SZ];
    __shared__ float s_acc[6];

    const int tid = threadIdx.x;
    if (tid < 6) s_acc[tid] = 0.f;

    const int b = tid >> 5;   // /32
    const int t = tid & 31;

    const float* tg = tgt + (size_t)(b * T_SZ + t) * 5;
    const float clsf = tg[0];
    const float xc = tg[1], yc = tg[2], w = tg[3], h = tg[4];
    const bool valid = (w > 0.f) && (h > 0.f);

    // best anchor: argmax IoU, first-max on ties (strict >)
    float best_iou = -1.f; int best_a = 0;
    #pragma unroll
    for (int a = 0; a < 3; ++a) {
        const float aw = AWC[s][a], ah = AHC[s][a];
        const float inter = fminf(w, aw) * fminf(h, ah);
        const float iou = inter / (w * h + aw * ah - inter + 1e-6f);
        if (iou > best_iou) { best_iou = iou; best_a = a; }
    }

    const float xw = xc * (float)W, yh = yc * (float)H;
    int gi = (int)xw; gi = min(max(gi, 0), W - 1);   // trunc like astype(int32)
    int gj = (int)yh; gj = min(max(gj, 0), H - 1);

    const int cell = valid ? (((b * 3 + best_a) * H + gj) * W + gi) : -1;
    s_cell[tid] = cell;
    s_cls[tid]  = (int)clsf;
    __syncthreads();

    // last-write-wins within a batch (numpy scatter semantics): the highest-t
    // target mapping to this cell is the "winner" that owns the box targets.
    bool winner = valid;
    if (valid) {
        #pragma unroll 1
        for (int t2 = t + 1; t2 < T_SZ; ++t2)
            if (s_cell[(b << 5) + t2] == cell) { winner = false; break; }
    }

    if (winner) {
        // class UNION over all targets in this batch hitting this cell
        // (tcls scatter sets distinct (cell, cls) pairs independently)
        unsigned um0 = 0, um1 = 0, um2 = 0;
        #pragma unroll 1
        for (int t2 = 0; t2 < T_SZ; ++t2) {
            if (s_cell[(b << 5) + t2] == cell) {
                const int c = s_cls[(b << 5) + t2];
                if (c < 32)      um0 |= 1u << c;
                else if (c < 64) um1 |= 1u << (c - 32);
                else             um2 |= 1u << (c - 64);
            }
        }

        const float txv = xw - (float)gi;
        const float tyv = yh - (float)gj;
        const float twv = logf(w / AWC[s][best_a] + 1e-6f);
        const float thv = logf(h / AHC[s][best_a] + 1e-6f);

        // pred[b, a, gj, gi, f] = orig[b, a*85+f, gj, gi]
        const float* Pb = P + ((size_t)(b * 255 + best_a * 85) * HW
                               + (size_t)gj * W + gi);
        const float px   = Pb[0];
        const float py   = Pb[(size_t)1 * HW];
        const float pw   = Pb[(size_t)2 * HW];
        const float ph   = Pb[(size_t)3 * HW];
        const float pobj = Pb[(size_t)4 * HW];

        const float d0 = sigmoidf_(px) - txv;
        const float d1 = sigmoidf_(py) - tyv;
        const float sxy = d0 * d0 + d1 * d1;
        const float e0 = pw - twv, e1 = ph - thv;
        const float swh = e0 * e0 + e1 * e1;
        const float spos  = focal1(pobj);
        const float snegc = focal0(pobj);   // subtract from the all-cells neg sum

        float scls = 0.f;
        #pragma unroll 1
        for (int c = 0; c < NUM_CLASSES; ++c) {
            const float x = Pb[(size_t)(5 + c) * HW];
            const bool ts = (c < 32) ? ((um0 >> c) & 1)
                          : (c < 64) ? ((um1 >> (c - 32)) & 1)
                                     : ((um2 >> (c - 64)) & 1);
            scls += ts ? focal1(x) : focal0(x);
        }

        atomicAdd(&s_acc[0], sxy);
        atomicAdd(&s_acc[1], swh);
        atomicAdd(&s_acc[2], scls);
        atomicAdd(&s_acc[3], spos);
        atomicAdd(&s_acc[4], -snegc);
        atomicAdd(&s_acc[5], 1.f);          // n_obj = count of distinct cells
    }
    __syncthreads();
    if (tid < 6) atomicAdd(&acc[s * 8 + tid], s_acc[tid]);
}

// ---- Kernel B: sum focal(pobj, 0) over ALL cells of all 3 scales ----
// Objectness planes (f=4) are contiguous HW-float runs; plane sizes are
// divisible by 4 and 16B-aligned -> float4 loads.
// float4 counts: scale0 76800, scale1 19200, scale2 4800 -> 100800 total.
__global__ void neg_kernel(const float* __restrict__ p0,
                           const float* __restrict__ p1,
                           const float* __restrict__ p2,
                           float* __restrict__ acc) {
    __shared__ float s_acc[3];
    if (threadIdx.x < 3) s_acc[threadIdx.x] = 0.f;
    __syncthreads();

    const int idx = blockIdx.x * blockDim.x + threadIdx.x;
    if (idx < 100800) {
        int s, q4, plane4;
        const float* P;
        if (idx < 76800)      { s = 0; P = p0; q4 = idx;          plane4 = 1600; }
        else if (idx < 96000) { s = 1; P = p1; q4 = idx - 76800;  plane4 = 400;  }
        else                  { s = 2; P = p2; q4 = idx - 96000;  plane4 = 100;  }
        const int plane = q4 / plane4;
        const int r4 = q4 - plane * plane4;
        const int b = plane / 3;
        const int a = plane - b * 3;
        const int HW = plane4 * 4;
        const float4 v = *reinterpret_cast<const float4*>(
            P + (size_t)(b * 255 + a * 85 + 4) * HW + (size_t)r4 * 4);
        const float sum = focal0(v.x) + focal0(v.y) + focal0(v.z) + focal0(v.w);
        atomicAdd(&s_acc[s], sum);
    }
    __syncthreads();
    if (threadIdx.x < 3) {
        const float v = s_acc[threadIdx.x];
        if (v != 0.f) atomicAdd(&acc[threadIdx.x * 8 + 4], v);
    }
}

// ---- Kernel C: finalize the scalar ----
__global__ void finalize_kernel(const float* __restrict__ acc,
                                float* __restrict__ out) {
    float total = 0.f;
    const int Ns0 = B_SZ * 3 * 80 * 80;
    const int Ns1 = B_SZ * 3 * 40 * 40;
    const int Ns2 = B_SZ * 3 * 20 * 20;
    const int Ns[3] = {Ns0, Ns1, Ns2};
    #pragma unroll 1
    for (int s = 0; s < 3; ++s) {
        const float* a = acc + s * 8;
        const float n_obj = a[5];
        const float n_noobj = (float)Ns[s] - n_obj;
        const float lxywh = (a[0] + a[1]) / fmaxf(2.f * n_obj, 1.f);
        const float lcls  = a[2] / fmaxf(n_obj * (float)NUM_CLASSES, 1.f);
        const float lpos  = a[3] / fmaxf(n_obj, 1.f);
        const float lneg  = a[4] / fmaxf(n_noobj, 1.f);
        const float has   = (n_obj > 0.f) ? 1.f : 0.f;
        total += 5.f * lxywh * has + 1.f * lpos * has + 0.5f * lneg + 1.f * lcls * has;
    }
    out[0] = total / 3.f;
}

extern "C" void kernel_launch(void* const* d_in, const int* in_sizes, int n_in,
                              void* d_out, int out_size, void* d_ws, size_t ws_size,
                              hipStream_t stream) {
    const float* p0  = (const float*)d_in[0];
    const float* p1  = (const float*)d_in[1];
    const float* p2  = (const float*)d_in[2];
    const float* tgt = (const float*)d_in[3];
    float* acc = (float*)d_ws;
    float* out = (float*)d_out;

    hipMemsetAsync(acc, 0, 24 * sizeof(float), stream);
    obj_kernel<<<3, B_SZ * T_SZ, 0, stream>>>(p0, p1, p2, tgt, acc);
    neg_kernel<<<394, 256, 0, stream>>>(p0, p1, p2, acc);
    finalize_kernel<<<1, 1, 0, stream>>>(acc, out);
}

// Round 2
// 40.924 us; speedup vs baseline: 3.7838x; 3.7838x over previous
//
#include <hip/hip_runtime.h>
#include <math.h>

#define NUM_CLASSES 80

// ---- math helpers (match jax.nn.log_sigmoid / sigmoid in f32) ----
__device__ __forceinline__ float softplusf_(float x) {
    return x > 0.f ? x + log1pf(expf(-x)) : log1pf(expf(x));
}
__device__ __forceinline__ float sigmoidf_(float x) {
    return 1.f / (1.f + expf(-x));
}
// focal_bce(x, t=0) = softplus(x) * sigmoid(x)^2
__device__ __forceinline__ float focal0(float x) {
    float s = sigmoidf_(x);
    return softplusf_(x) * s * s;
}
// focal_bce(x, t=1) = softplus(-x) * sigmoid(-x)^2
__device__ __forceinline__ float focal1(float x) {
    float s = sigmoidf_(-x);
    return softplusf_(-x) * s * s;
}

// ws layout (floats):
//   [0..2]   : all-cell focal(pobj,0) sums per scale (neg_kernel atomics)
//   [32 + bid*8 .. +7] : per-(s,b,t) partial slot:
//       [0]=xy [1]=wh [2]=cls [3]=pos [4]=neg_corr [5]=count [6,7]=0

// ---- Kernel O: one block per (scale, batch, target) ----
// 1536 blocks x 128 threads. Lanes 0..31 rebuild the batch's cell table in
// LDS; lane f (<85) gathers channel f of the winner cell. One latency round.
__global__ void obj_kernel(const float* __restrict__ p0,
                           const float* __restrict__ p1,
                           const float* __restrict__ p2,
                           const float* __restrict__ tgt,
                           float* __restrict__ ws) {
    const int bid = blockIdx.x;
    const int s = bid >> 9;          // /512
    const int r = bid & 511;
    const int b = r >> 5;            // /32
    const int t = r & 31;

    const int H  = (s == 0) ? 80 : (s == 1 ? 40 : 20);
    const int W  = H;
    const int HW = H * W;

    // ANCHORS[s] / 640 in registers (no runtime-indexed arrays -> no scratch)
    float aw0, aw1, aw2, ah0, ah1, ah2;
    if (s == 0) { aw0=10.f/640.f; aw1=16.f/640.f; aw2=33.f/640.f;
                  ah0=13.f/640.f; ah1=30.f/640.f; ah2=23.f/640.f; }
    else if (s == 1) { aw0=30.f/640.f; aw1=62.f/640.f; aw2=59.f/640.f;
                       ah0=61.f/640.f; ah1=45.f/640.f; ah2=119.f/640.f; }
    else { aw0=116.f/640.f; aw1=156.f/640.f; aw2=373.f/640.f;
           ah0=90.f/640.f;  ah1=198.f/640.f; ah2=326.f/640.f; }

    __shared__ int   s_cell[32];
    __shared__ int   s_cls [32];
    __shared__ float s_sum[5];

    const int f = threadIdx.x;
    if (f < 5) s_sum[f] = 0.f;

    if (f < 32) {
        const float* tg = tgt + (size_t)(b * 32 + f) * 5;
        const float w = tg[3], h = tg[4];
        int cell = -1;
        if (w > 0.f && h > 0.f) {
            // argmax IoU over 3 anchors, first-max on ties (strict >)
            float best = -1.f; int ba = 0;
            {
                float inter = fminf(w, aw0) * fminf(h, ah0);
                float iou = inter / (w * h + aw0 * ah0 - inter + 1e-6f);
                if (iou > best) { best = iou; ba = 0; }
                inter = fminf(w, aw1) * fminf(h, ah1);
                iou = inter / (w * h + aw1 * ah1 - inter + 1e-6f);
                if (iou > best) { best = iou; ba = 1; }
                inter = fminf(w, aw2) * fminf(h, ah2);
                iou = inter / (w * h + aw2 * ah2 - inter + 1e-6f);
                if (iou > best) { best = iou; ba = 2; }
            }
            const float xw = tg[1] * (float)W, yh = tg[2] * (float)H;
            int gi = (int)xw; gi = min(max(gi, 0), W - 1);  // trunc == astype(i32)
            int gj = (int)yh; gj = min(max(gj, 0), H - 1);
            cell = (ba * H + gj) * W + gi;                  // b uniform in block
        }
        s_cell[f] = cell;
        s_cls[f]  = (int)tg[0];
    }
    __syncthreads();

    const int mycell = s_cell[t];
    bool winner = (mycell >= 0);
    if (winner) {
        // numpy scatter = last-write-wins in t order within the batch
        #pragma unroll 1
        for (int t2 = t + 1; t2 < 32; ++t2)
            if (s_cell[t2] == mycell) { winner = false; break; }
    }

    float* slot = ws + 32 + (size_t)bid * 8;
    if (!winner) {                        // uniform across the block
        if (f < 8) slot[f] = 0.f;
        return;
    }

    // class UNION over all targets hitting this cell
    unsigned um0 = 0, um1 = 0, um2 = 0;
    #pragma unroll 1
    for (int t2 = 0; t2 < 32; ++t2) {
        if (s_cell[t2] == mycell) {
            const int c = s_cls[t2];
            if (c < 32)      um0 |= 1u << c;
            else if (c < 64) um1 |= 1u << (c - 32);
            else             um2 |= 1u << (c - 64);
        }
    }

    // geometry of target t (uniform; recomputed by all lanes)
    const float* tg = tgt + (size_t)(b * 32 + t) * 5;
    const float w = tg[3], h = tg[4];
    float best = -1.f; int ba = 0;
    {
        float inter = fminf(w, aw0) * fminf(h, ah0);
        float iou = inter / (w * h + aw0 * ah0 - inter + 1e-6f);
        if (iou > best) { best = iou; ba = 0; }
        inter = fminf(w, aw1) * fminf(h, ah1);
        iou = inter / (w * h + aw1 * ah1 - inter + 1e-6f);
        if (iou > best) { best = iou; ba = 1; }
        inter = fminf(w, aw2) * fminf(h, ah2);
        iou = inter / (w * h + aw2 * ah2 - inter + 1e-6f);
        if (iou > best) { best = iou; ba = 2; }
    }
    const float aw = (ba == 0) ? aw0 : (ba == 1 ? aw1 : aw2);
    const float ah = (ba == 0) ? ah0 : (ba == 1 ? ah1 : ah2);
    const float xw = tg[1] * (float)W, yh = tg[2] * (float)H;
    int gi = (int)xw; gi = min(max(gi, 0), W - 1);
    int gj = (int)yh; gj = min(max(gj, 0), H - 1);

    if (f < 85) {
        const float* P = (s == 0) ? p0 : (s == 1 ? p1 : p2);
        const float val = P[(size_t)(b * 255 + ba * 85 + f) * HW
                            + (size_t)gj * W + gi];
        float contrib; int cat;
        if (f == 0) {
            const float d = sigmoidf_(val) - (xw - (float)gi);
            contrib = d * d; cat = 0;
        } else if (f == 1) {
            const float d = sigmoidf_(val) - (yh - (float)gj);
            contrib = d * d; cat = 0;
        } else if (f == 2) {
            const float e = val - logf(w / aw + 1e-6f);
            contrib = e * e; cat = 1;
        } else if (f == 3) {
            const float e = val - logf(h / ah + 1e-6f);
            contrib = e * e; cat = 1;
        } else if (f == 4) {
            contrib = focal1(val); cat = 3;
            atomicAdd(&s_sum[4], -focal0(val));   // correction to all-cell neg sum
        } else {
            const int c = f - 5;
            const bool ts = (c < 32) ? ((um0 >> c) & 1)
                          : (c < 64) ? ((um1 >> (c - 32)) & 1)
                                     : ((um2 >> (c - 64)) & 1);
            contrib = ts ? focal1(val) : focal0(val); cat = 2;
        }
        atomicAdd(&s_sum[cat], contrib);
    }
    __syncthreads();
    if (f < 5)       slot[f] = s_sum[f];
    else if (f == 5) slot[5] = 1.f;       // this block is one object cell
    else if (f < 8)  slot[f] = 0.f;
}

// ---- Kernel N: sum focal(pobj, 0) over ALL cells of all 3 scales ----
// float4 counts: scale0 76800, scale1 19200, scale2 4800 -> 100800 total.
__global__ void neg_kernel(const float* __restrict__ p0,
                           const float* __restrict__ p1,
                           const float* __restrict__ p2,
                           float* __restrict__ ws) {
    __shared__ float s_acc[3];
    if (threadIdx.x < 3) s_acc[threadIdx.x] = 0.f;
    __syncthreads();

    const int idx = blockIdx.x * blockDim.x + threadIdx.x;
    if (idx < 100800) {
        int s, q4, plane4;
        const float* P;
        if (idx < 76800)      { s = 0; P = p0; q4 = idx;          plane4 = 1600; }
        else if (idx < 96000) { s = 1; P = p1; q4 = idx - 76800;  plane4 = 400;  }
        else                  { s = 2; P = p2; q4 = idx - 96000;  plane4 = 100;  }
        const int plane = q4 / plane4;
        const int r4 = q4 - plane * plane4;
        const int b = plane / 3;
        const int a = plane - b * 3;
        const int HW = plane4 * 4;
        const float4 v = *reinterpret_cast<const float4*>(
            P + (size_t)(b * 255 + a * 85 + 4) * HW + (size_t)r4 * 4);
        const float sum = focal0(v.x) + focal0(v.y) + focal0(v.z) + focal0(v.w);
        atomicAdd(&s_acc[s], sum);
    }
    __syncthreads();
    if (threadIdx.x < 3) {
        const float v = s_acc[threadIdx.x];
        if (v != 0.f) atomicAdd(&ws[threadIdx.x], v);
    }
}

// ---- Kernel F: reduce 1536 partial slots + finalize scalar ----
__global__ void finalize_kernel(const float* __restrict__ ws,
                                float* __restrict__ out) {
    __shared__ float s_red[8 * 6];
    __shared__ float s_total;
    const int tid  = threadIdx.x;            // 512 threads
    const int lane = tid & 63;
    const int wid  = tid >> 6;
    if (tid == 0) s_total = 0.f;

    #pragma unroll 1
    for (int s = 0; s < 3; ++s) {
        const float* slot = ws + 32 + (size_t)(s * 512 + tid) * 8;
        float v[6];
        #pragma unroll
        for (int k = 0; k < 6; ++k) v[k] = slot[k];
        #pragma unroll
        for (int off = 32; off; off >>= 1)
            #pragma unroll
            for (int k = 0; k < 6; ++k) v[k] += __shfl_down(v[k], off);
        if (lane == 0) {
            #pragma unroll
            for (int k = 0; k < 6; ++k) s_red[wid * 6 + k] = v[k];
        }
        __syncthreads();
        if (tid == 0) {
            float sum[6] = {0.f, 0.f, 0.f, 0.f, 0.f, 0.f};
            for (int wv = 0; wv < 8; ++wv)
                #pragma unroll
                for (int k = 0; k < 6; ++k) sum[k] += s_red[wv * 6 + k];
            const float Ns = (s == 0) ? (float)(16 * 3 * 6400)
                           : (s == 1) ? (float)(16 * 3 * 1600)
                                      : (float)(16 * 3 * 400);
            const float n_obj   = sum[5];
            const float n_noobj = Ns - n_obj;
            const float lxywh = (sum[0] + sum[1]) / fmaxf(2.f * n_obj, 1.f);
            const float lcls  = sum[2] / fmaxf(n_obj * (float)NUM_CLASSES, 1.f);
            const float lpos  = sum[3] / fmaxf(n_obj, 1.f);
            const float lneg  = (ws[s] + sum[4]) / fmaxf(n_noobj, 1.f);
            const float has   = (n_obj > 0.f) ? 1.f : 0.f;
            s_total += 5.f * lxywh * has + lpos * has + 0.5f * lneg + lcls * has;
        }
        __syncthreads();
    }
    if (tid == 0) out[0] = s_total / 3.f;
}

extern "C" void kernel_launch(void* const* d_in, const int* in_sizes, int n_in,
                              void* d_out, int out_size, void* d_ws, size_t ws_size,
                              hipStream_t stream) {
    const float* p0  = (const float*)d_in[0];
    const float* p1  = (const float*)d_in[1];
    const float* p2  = (const float*)d_in[2];
    const float* tgt = (const float*)d_in[3];
    float* ws  = (float*)d_ws;   // needs 32 + 1536*8 floats ~= 49 KB
    float* out = (float*)d_out;

    hipMemsetAsync(ws, 0, 32 * sizeof(float), stream);
    neg_kernel<<<394, 256, 0, stream>>>(p0, p1, p2, ws);
    obj_kernel<<<1536, 128, 0, stream>>>(p0, p1, p2, tgt, ws);
    finalize_kernel<<<1, 512, 0, stream>>>(ws, out);
}

// Round 3
// 40.684 us; speedup vs baseline: 3.8061x; 1.0059x over previous
//
#include <hip/hip_runtime.h>
#include <math.h>

#define NUM_CLASSES 80

// ---- math helpers (match jax.nn.log_sigmoid / sigmoid in f32) ----
__device__ __forceinline__ float softplusf_(float x) {
    return x > 0.f ? x + log1pf(expf(-x)) : log1pf(expf(x));
}
__device__ __forceinline__ float sigmoidf_(float x) {
    return 1.f / (1.f + expf(-x));
}
// focal_bce(x, t=0) = softplus(x) * sigmoid(x)^2
__device__ __forceinline__ float focal0(float x) {
    float s = sigmoidf_(x);
    return softplusf_(x) * s * s;
}
// focal_bce(x, t=1) = softplus(-x) * sigmoid(-x)^2
__device__ __forceinline__ float focal1(float x) {
    float s = sigmoidf_(-x);
    return softplusf_(-x) * s * s;
}

// ws layout (floats):
//   [0..2]   : all-cell focal(pobj,0) sums per scale (neg_kernel atomics)
//   [32 + bid*8 .. +7] : per-(s,b,t) partial slot:
//       [0]=xy [1]=wh [2]=cls [3]=pos [4]=neg_corr [5]=count [6,7]=0

// ---- Kernel O: one block per (scale, batch, target) ----
// 1536 blocks x 128 threads. Lanes 0..31 rebuild the batch's cell table in
// LDS; lane f (<85) gathers channel f of the winner cell. One latency round.
__global__ void obj_kernel(const float* __restrict__ p0,
                           const float* __restrict__ p1,
                           const float* __restrict__ p2,
                           const float* __restrict__ tgt,
                           float* __restrict__ ws) {
    const int bid = blockIdx.x;
    const int s = bid >> 9;          // /512
    const int r = bid & 511;
    const int b = r >> 5;            // /32
    const int t = r & 31;

    const int H  = (s == 0) ? 80 : (s == 1 ? 40 : 20);
    const int W  = H;
    const int HW = H * W;

    // ANCHORS[s] / 640 in registers (no runtime-indexed arrays -> no scratch)
    float aw0, aw1, aw2, ah0, ah1, ah2;
    if (s == 0) { aw0=10.f/640.f; aw1=16.f/640.f; aw2=33.f/640.f;
                  ah0=13.f/640.f; ah1=30.f/640.f; ah2=23.f/640.f; }
    else if (s == 1) { aw0=30.f/640.f; aw1=62.f/640.f; aw2=59.f/640.f;
                       ah0=61.f/640.f; ah1=45.f/640.f; ah2=119.f/640.f; }
    else { aw0=116.f/640.f; aw1=156.f/640.f; aw2=373.f/640.f;
           ah0=90.f/640.f;  ah1=198.f/640.f; ah2=326.f/640.f; }

    __shared__ int   s_cell[32];
    __shared__ int   s_cls [32];
    __shared__ float s_sum[5];

    const int f = threadIdx.x;
    if (f < 5) s_sum[f] = 0.f;

    if (f < 32) {
        const float* tg = tgt + (size_t)(b * 32 + f) * 5;
        const float w = tg[3], h = tg[4];
        int cell = -1;
        if (w > 0.f && h > 0.f) {
            // argmax IoU over 3 anchors, first-max on ties (strict >)
            float best = -1.f; int ba = 0;
            {
                float inter = fminf(w, aw0) * fminf(h, ah0);
                float iou = inter / (w * h + aw0 * ah0 - inter + 1e-6f);
                if (iou > best) { best = iou; ba = 0; }
                inter = fminf(w, aw1) * fminf(h, ah1);
                iou = inter / (w * h + aw1 * ah1 - inter + 1e-6f);
                if (iou > best) { best = iou; ba = 1; }
                inter = fminf(w, aw2) * fminf(h, ah2);
                iou = inter / (w * h + aw2 * ah2 - inter + 1e-6f);
                if (iou > best) { best = iou; ba = 2; }
            }
            const float xw = tg[1] * (float)W, yh = tg[2] * (float)H;
            int gi = (int)xw; gi = min(max(gi, 0), W - 1);  // trunc == astype(i32)
            int gj = (int)yh; gj = min(max(gj, 0), H - 1);
            cell = (ba * H + gj) * W + gi;                  // b uniform in block
        }
        s_cell[f] = cell;
        s_cls[f]  = (int)tg[0];
    }
    __syncthreads();

    const int mycell = s_cell[t];
    bool winner = (mycell >= 0);
    if (winner) {
        // numpy scatter = last-write-wins in t order within the batch
        #pragma unroll 1
        for (int t2 = t + 1; t2 < 32; ++t2)
            if (s_cell[t2] == mycell) { winner = false; break; }
    }

    float* slot = ws + 32 + (size_t)bid * 8;
    if (!winner) {                        // uniform across the block
        if (f < 8) slot[f] = 0.f;
        return;
    }

    // class UNION over all targets hitting this cell
    unsigned um0 = 0, um1 = 0, um2 = 0;
    #pragma unroll 1
    for (int t2 = 0; t2 < 32; ++t2) {
        if (s_cell[t2] == mycell) {
            const int c = s_cls[t2];
            if (c < 32)      um0 |= 1u << c;
            else if (c < 64) um1 |= 1u << (c - 32);
            else             um2 |= 1u << (c - 64);
        }
    }

    // geometry of target t (uniform; recomputed by all lanes)
    const float* tg = tgt + (size_t)(b * 32 + t) * 5;
    const float w = tg[3], h = tg[4];
    float best = -1.f; int ba = 0;
    {
        float inter = fminf(w, aw0) * fminf(h, ah0);
        float iou = inter / (w * h + aw0 * ah0 - inter + 1e-6f);
        if (iou > best) { best = iou; ba = 0; }
        inter = fminf(w, aw1) * fminf(h, ah1);
        iou = inter / (w * h + aw1 * ah1 - inter + 1e-6f);
        if (iou > best) { best = iou; ba = 1; }
        inter = fminf(w, aw2) * fminf(h, ah2);
        iou = inter / (w * h + aw2 * ah2 - inter + 1e-6f);
        if (iou > best) { best = iou; ba = 2; }
    }
    const float aw = (ba == 0) ? aw0 : (ba == 1 ? aw1 : aw2);
    const float ah = (ba == 0) ? ah0 : (ba == 1 ? ah1 : ah2);
    const float xw = tg[1] * (float)W, yh = tg[2] * (float)H;
    int gi = (int)xw; gi = min(max(gi, 0), W - 1);
    int gj = (int)yh; gj = min(max(gj, 0), H - 1);

    if (f < 85) {
        const float* P = (s == 0) ? p0 : (s == 1 ? p1 : p2);
        const float val = P[(size_t)(b * 255 + ba * 85 + f) * HW
                            + (size_t)gj * W + gi];
        float contrib; int cat;
        if (f == 0) {
            const float d = sigmoidf_(val) - (xw - (float)gi);
            contrib = d * d; cat = 0;
        } else if (f == 1) {
            const float d = sigmoidf_(val) - (yh - (float)gj);
            contrib = d * d; cat = 0;
        } else if (f == 2) {
            const float e = val - logf(w / aw + 1e-6f);
            contrib = e * e; cat = 1;
        } else if (f == 3) {
            const float e = val - logf(h / ah + 1e-6f);
            contrib = e * e; cat = 1;
        } else if (f == 4) {
            contrib = focal1(val); cat = 3;
            atomicAdd(&s_sum[4], -focal0(val));   // correction to all-cell neg sum
        } else {
            const int c = f - 5;
            const bool ts = (c < 32) ? ((um0 >> c) & 1)
                          : (c < 64) ? ((um1 >> (c - 32)) & 1)
                                     : ((um2 >> (c - 64)) & 1);
            contrib = ts ? focal1(val) : focal0(val); cat = 2;
        }
        atomicAdd(&s_sum[cat], contrib);
    }
    __syncthreads();
    if (f < 5)       slot[f] = s_sum[f];
    else if (f == 5) slot[5] = 1.f;       // this block is one object cell
    else if (f < 8)  slot[f] = 0.f;
}

// ---- Kernel N: sum focal(pobj, 0) over ALL cells of all 3 scales ----
// float4 counts: scale0 76800, scale1 19200, scale2 4800 -> 100800 total.
__global__ void neg_kernel(const float* __restrict__ p0,
                           const float* __restrict__ p1,
                           const float* __restrict__ p2,
                           float* __restrict__ ws) {
    __shared__ float s_acc[3];
    if (threadIdx.x < 3) s_acc[threadIdx.x] = 0.f;
    __syncthreads();

    const int idx = blockIdx.x * blockDim.x + threadIdx.x;
    if (idx < 100800) {
        int s, q4, plane4;
        const float* P;
        if (idx < 76800)      { s = 0; P = p0; q4 = idx;          plane4 = 1600; }
        else if (idx < 96000) { s = 1; P = p1; q4 = idx - 76800;  plane4 = 400;  }
        else                  { s = 2; P = p2; q4 = idx - 96000;  plane4 = 100;  }
        const int plane = q4 / plane4;
        const int r4 = q4 - plane * plane4;
        const int b = plane / 3;
        const int a = plane - b * 3;
        const int HW = plane4 * 4;
        const float4 v = *reinterpret_cast<const float4*>(
            P + (size_t)(b * 255 + a * 85 + 4) * HW + (size_t)r4 * 4);
        const float sum = focal0(v.x) + focal0(v.y) + focal0(v.z) + focal0(v.w);
        atomicAdd(&s_acc[s], sum);
    }
    __syncthreads();
    if (threadIdx.x < 3) {
        const float v = s_acc[threadIdx.x];
        if (v != 0.f) atomicAdd(&ws[threadIdx.x], v);
    }
}

// ---- Kernel F: reduce 1536 partial slots + finalize scalar ----
__global__ void finalize_kernel(const float* __restrict__ ws,
                                float* __restrict__ out) {
    __shared__ float s_red[8 * 6];
    __shared__ float s_total;
    const int tid  = threadIdx.x;            // 512 threads
    const int lane = tid & 63;
    const int wid  = tid >> 6;
    if (tid == 0) s_total = 0.f;

    #pragma unroll 1
    for (int s = 0; s < 3; ++s) {
        const float* slot = ws + 32 + (size_t)(s * 512 + tid) * 8;
        float v[6];
        #pragma unroll
        for (int k = 0; k < 6; ++k) v[k] = slot[k];
        #pragma unroll
        for (int off = 32; off; off >>= 1)
            #pragma unroll
            for (int k = 0; k < 6; ++k) v[k] += __shfl_down(v[k], off);
        if (lane == 0) {
            #pragma unroll
            for (int k = 0; k < 6; ++k) s_red[wid * 6 + k] = v[k];
        }
        __syncthreads();
        if (tid == 0) {
            float sum[6] = {0.f, 0.f, 0.f, 0.f, 0.f, 0.f};
            for (int wv = 0; wv < 8; ++wv)
                #pragma unroll
                for (int k = 0; k < 6; ++k) sum[k] += s_red[wv * 6 + k];
            const float Ns = (s == 0) ? (float)(16 * 3 * 6400)
                           : (s == 1) ? (float)(16 * 3 * 1600)
                                      : (float)(16 * 3 * 400);
            const float n_obj   = sum[5];
            const float n_noobj = Ns - n_obj;
            const float lxywh = (sum[0] + sum[1]) / fmaxf(2.f * n_obj, 1.f);
            const float lcls  = sum[2] / fmaxf(n_obj * (float)NUM_CLASSES, 1.f);
            const float lpos  = sum[3] / fmaxf(n_obj, 1.f);
            const float lneg  = (ws[s] + sum[4]) / fmaxf(n_noobj, 1.f);
            const float has   = (n_obj > 0.f) ? 1.f : 0.f;
            s_total += 5.f * lxywh * has + lpos * has + 0.5f * lneg + lcls * has;
        }
        __syncthreads();
    }
    if (tid == 0) out[0] = s_total / 3.f;
}

extern "C" void kernel_launch(void* const* d_in, const int* in_sizes, int n_in,
                              void* d_out, int out_size, void* d_ws, size_t ws_size,
                              hipStream_t stream) {
    const float* p0  = (const float*)d_in[0];
    const float* p1  = (const float*)d_in[1];
    const float* p2  = (const float*)d_in[2];
    const float* tgt = (const float*)d_in[3];
    float* ws  = (float*)d_ws;   // needs 32 + 1536*8 floats ~= 49 KB
    float* out = (float*)d_out;

    hipMemsetAsync(ws, 0, 32 * sizeof(float), stream);
    neg_kernel<<<394, 256, 0, stream>>>(p0, p1, p2, ws);
    obj_kernel<<<1536, 128, 0, stream>>>(p0, p1, p2, tgt, ws);
    finalize_kernel<<<1, 512, 0, stream>>>(ws, out);
}